// Round 16
// baseline (699.194 us; speedup 1.0000x reference)
//
#include <hip/hip_runtime.h>
#include <math.h>

namespace {

constexpr int B  = 4;
constexpr int S  = 1024;
constexpr int D  = 768;
constexpr int H  = 12;
constexpr int HD = 64;
constexpr int F  = 3072;
constexpr int L  = 4;
constexpr int M  = B * S;       // 4096 tokens
constexpr int NQKV = 3 * D;     // 2304
constexpr int NQK = 2 * D;      // 1536 (q|k packed)

typedef __attribute__((ext_vector_type(4))) float    f32x4;
typedef _Float16 f16x8 __attribute__((ext_vector_type(8)));
typedef __attribute__((ext_vector_type(8))) unsigned short u16x8;
typedef __attribute__((ext_vector_type(4))) unsigned short u16x4;

__device__ __forceinline__ unsigned short f2h_u(float f) {
    _Float16 h = (_Float16)f;
    return __builtin_bit_cast(unsigned short, h);
}
__device__ __forceinline__ float h2f(unsigned short u) {
    return (float)__builtin_bit_cast(_Float16, u);
}

__device__ __forceinline__ void gload16(const void* gptr, void* ldsptr) {
    __builtin_amdgcn_global_load_lds(
        (const __attribute__((address_space(1))) unsigned int*)gptr,
        (__attribute__((address_space(3))) unsigned int*)ldsptr,
        16, 0, 0);
}

// ---------------- reductions ----------------
__device__ __forceinline__ float wave_sum(float v) {
#pragma unroll
    for (int off = 32; off; off >>= 1) v += __shfl_xor(v, off, 64);
    return v;
}
// 192-thread (3-wave) block reduce
__device__ __forceinline__ float block_sum192(float v, float* sm) {
    v = wave_sum(v);
    __syncthreads();
    if ((threadIdx.x & 63) == 0) sm[threadIdx.x >> 6] = v;
    __syncthreads();
    return sm[0] + sm[1] + sm[2];
}

// ---------------- fused weight prep: pipelined 64x256 chunks ----------------
// fp32 [R][C] -> fp16 [C][R]. Each block: 4 consecutive 64x64 tiles; next tile's
// global loads are issued between the barriers so HBM latency hides under the
// LDS-read/convert/store phase of the current tile (round-15 profile: 3.1 TB/s,
// latency-exposed read->barrier->write->exit blocks).
__device__ __forceinline__ void transpose_stripe4(const float* __restrict__ src,
                                                  unsigned short* __restrict__ dst,
                                                  int R, int C, int rb, int cb0) {
    __shared__ float tile[64][65];
    const int t = threadIdx.x;
    const int r = t >> 2;           // 0..63 (src row within tile)
    const int q4 = t & 3;
    const int dc = t >> 2;          // 0..63 (dst row within tile)
    const int s8 = t & 3;

    float4 rv[4];
    // prologue: load tile 0
#pragma unroll
    for (int k = 0; k < 4; ++k)
        rv[k] = *(const float4*)&src[(size_t)(rb + r) * C + cb0 + (q4 + k * 4) * 4];

#pragma unroll
    for (int j = 0; j < 4; ++j) {
        const int cb = cb0 + j * 64;
        // write regs -> LDS (compiler waits vmcnt for rv here)
#pragma unroll
        for (int k = 0; k < 4; ++k) {
            const int cq = (q4 + k * 4) * 4;
            tile[r][cq + 0] = rv[k].x; tile[r][cq + 1] = rv[k].y;
            tile[r][cq + 2] = rv[k].z; tile[r][cq + 3] = rv[k].w;
        }
        __syncthreads();
        // issue next tile's loads now: they complete during the store phase below
        if (j < 3) {
#pragma unroll
            for (int k = 0; k < 4; ++k)
                rv[k] = *(const float4*)&src[(size_t)(rb + r) * C + cb0 + (j + 1) * 64 + (q4 + k * 4) * 4];
        }
        // store phase: read LDS columns, convert, full-128B-line writes
#pragma unroll
        for (int k = 0; k < 2; ++k) {
            const int rq = (s8 + k * 4) * 8;
            u16x8 o;
#pragma unroll
            for (int jj = 0; jj < 8; ++jj) o[jj] = f2h_u(tile[rq + jj][dc]);
            *(u16x8*)&dst[(size_t)(cb + dc) * R + rb + rq] = o;
        }
        __syncthreads();   // all LDS reads done before next overwrite
    }
}

__global__ __launch_bounds__(256) void weight_prep_kernel(
    const float* __restrict__ Wq, const float* __restrict__ Wk,
    const float* __restrict__ Wv, const float* __restrict__ Wo,
    const float* __restrict__ W1, const float* __restrict__ W2,
    const float* __restrict__ bq, const float* __restrict__ bk,
    const float* __restrict__ bv,
    unsigned short* __restrict__ Wqkv_t, unsigned short* __restrict__ Wo_t,
    unsigned short* __restrict__ W1_t, unsigned short* __restrict__ W2_t,
    float* __restrict__ bqkv) {
    const int c = blockIdx.x;
    if (c < 576) {                          // Wq/Wk/Wv/Wo : DxD, 36 chunks each
        const int mat = c / 36, rc = c % 36;
        const int l = mat >> 2, which = mat & 3;
        const float* src = (which == 0 ? Wq : which == 1 ? Wk : which == 2 ? Wv : Wo)
                           + (size_t)l * D * D;
        unsigned short* dst = (which < 3)
            ? Wqkv_t + ((size_t)l * NQKV + which * D) * D
            : Wo_t + (size_t)l * D * D;
        transpose_stripe4(src, dst, D, D, (rc / 3) * 64, (rc % 3) * 256);
    } else if (c < 1152) {                  // W1 : R=D, C=F -> [F][D], 144 chunks/l
        const int c2 = c - 576, l = c2 / 144, rc = c2 % 144;
        transpose_stripe4(W1 + (size_t)l * D * F, W1_t + (size_t)l * F * D,
                          D, F, (rc / 12) * 64, (rc % 12) * 256);
    } else if (c < 1728) {                  // W2 : R=F, C=D -> [D][F], 144 chunks/l
        const int c2 = c - 1152, l = c2 / 144, rc = c2 % 144;
        transpose_stripe4(W2 + (size_t)l * F * D, W2_t + (size_t)l * D * F,
                          F, D, (rc / 3) * 64, (rc % 3) * 256);
    } else {                                // bias concat (36 blocks)
        const int i = (c - 1728) * 256 + threadIdx.x;
        if (i < L * NQKV) {
            const int l = i / NQKV, j = i % NQKV;
            bqkv[i] = (j < D) ? bq[l * D + j]
                    : (j < 2 * D) ? bk[l * D + j - D] : bv[l * D + j - 2 * D];
        }
    }
}

// ---------------- embeddings + LayerNorm -> fp16 stream (192 thr) ------
__global__ __launch_bounds__(192) void embed_ln_kernel(
    const int* __restrict__ x, const float* __restrict__ we,
    const float* __restrict__ pe, const float* __restrict__ te,
    const float* __restrict__ g, const float* __restrict__ bb,
    unsigned short* __restrict__ hh) {
    __shared__ float sm[3];
    const int row = blockIdx.x;
    const int s = row & (S - 1);
    const int tok = x[row];
    const int t = threadIdx.x;
    const int d = t * 4;
    float v[4];
    const float4 w = *(const float4*)&we[(size_t)tok * D + d];
    const float4 p = *(const float4*)&pe[(size_t)s * D + d];
    const float4 tt = *(const float4*)&te[d];
    v[0] = w.x + p.x + tt.x; v[1] = w.y + p.y + tt.y;
    v[2] = w.z + p.z + tt.z; v[3] = w.w + p.w + tt.w;
    const float mu = block_sum192(v[0] + v[1] + v[2] + v[3], sm) * (1.0f / D);
    float lvar = 0.f;
#pragma unroll
    for (int i = 0; i < 4; ++i) { float dv = v[i] - mu; lvar += dv * dv; }
    const float var = block_sum192(lvar, sm) * (1.0f / D);
    const float inv = rsqrtf(var + 1e-12f);
    const float4 g4 = *(const float4*)&g[d];
    const float4 b4 = *(const float4*)&bb[d];
    u16x4 ob;
    ob[0] = f2h_u((v[0] - mu) * inv * g4.x + b4.x);
    ob[1] = f2h_u((v[1] - mu) * inv * g4.y + b4.y);
    ob[2] = f2h_u((v[2] - mu) * inv * g4.z + b4.z);
    ob[3] = f2h_u((v[3] - mu) * inv * g4.w + b4.w);
    *(u16x4*)&hh[(size_t)row * D + d] = ob;
}

// ------- partial-sum reduce + (opt GELU / fp16 residual) + LayerNorm (192 thr) -----
template <int NPA, int NPB, bool GELU_, bool HAS_RES>
__global__ __launch_bounds__(192) void ln_reduce_kernel(
    const unsigned short* __restrict__ pA,
    const unsigned short* __restrict__ pB,
    const float* __restrict__ bias,
    const unsigned short* __restrict__ res,
    const float* __restrict__ g, const float* __restrict__ bb,
    unsigned short* __restrict__ outh) {
    __shared__ float sm[3];
    const int row = blockIdx.x;
    const int t = threadIdx.x;
    const int d = t * 4;
    float v[4];
    const float4 bi = *(const float4*)&bias[d];
    v[0] = bi.x; v[1] = bi.y; v[2] = bi.z; v[3] = bi.w;
#pragma unroll
    for (int pp = 0; pp < NPA; ++pp) {
        const u16x4 pu = *(const u16x4*)&pA[(size_t)pp * M * D + (size_t)row * D + d];
#pragma unroll
        for (int i = 0; i < 4; ++i) v[i] += h2f(pu[i]);
    }
#pragma unroll
    for (int pp = 0; pp < NPB; ++pp) {
        const u16x4 pu = *(const u16x4*)&pB[(size_t)pp * M * D + (size_t)row * D + d];
#pragma unroll
        for (int i = 0; i < 4; ++i) v[i] += h2f(pu[i]);
    }
    if (HAS_RES) {
        const u16x4 rv = *(const u16x4*)&res[(size_t)row * D + d];
#pragma unroll
        for (int i = 0; i < 4; ++i) v[i] += h2f(rv[i]);
    }
    if (GELU_) {
#pragma unroll
        for (int i = 0; i < 4; ++i)
            v[i] = 0.5f * v[i] * (1.0f + erff(v[i] * 0.70710678118654752f));
    }
    const float mu = block_sum192(v[0] + v[1] + v[2] + v[3], sm) * (1.0f / D);
    float lvar = 0.f;
#pragma unroll
    for (int i = 0; i < 4; ++i) { float dv = v[i] - mu; lvar += dv * dv; }
    const float var = block_sum192(lvar, sm) * (1.0f / D);
    const float inv = rsqrtf(var + 1e-12f);
    const float4 g4 = *(const float4*)&g[d];
    const float4 b4 = *(const float4*)&bb[d];
    u16x4 ob;
    ob[0] = f2h_u((v[0] - mu) * inv * g4.x + b4.x);
    ob[1] = f2h_u((v[1] - mu) * inv * g4.y + b4.y);
    ob[2] = f2h_u((v[2] - mu) * inv * g4.z + b4.z);
    ob[3] = f2h_u((v[3] - mu) * inv * g4.w + b4.w);
    *(u16x4*)&outh[(size_t)row * D + d] = ob;
}

// ======== shared fp16 MFMA GEMM body: 128x128 tile, BK=32, 4 waves ========
// 3-buffer pipeline, counted vmcnt(4); T1 XCD-swizzled block ids; T5 setprio.
// 48 KB LDS -> 3 blocks/CU (proven optimum: 72 KB/2-blk was -45%, 32 KB/5-blk neutral).
#define GEMM_STAGE(buf, k0)                                                          \
    do {                                                                             \
        gload16(Ab + (size_t)(rowBase + r0) * LDA + (k0) + c0 * 8, &Asl[buf][ldsOff0]); \
        gload16(Ab + (size_t)(rowBase + r1) * LDA + (k0) + c1 * 8, &Asl[buf][ldsOff1]); \
        gload16(Bb + (size_t)(colBase + r0) * LDA + (k0) + c0 * 8, &Bsl[buf][ldsOff0]); \
        gload16(Bb + (size_t)(colBase + r1) * LDA + (k0) + c1 * 8, &Bsl[buf][ldsOff1]); \
    } while (0)

#define GEMM_BODY(A_, Bw_, LDA_, KLEN_)                                              \
    constexpr int BK = 32;                                                           \
    __shared__ unsigned short Asl[3][128 * BK];                                      \
    __shared__ unsigned short Bsl[3][128 * BK];                                      \
    const unsigned short* Ab = (A_);                                                 \
    const unsigned short* Bb = (Bw_);                                                \
    const int LDA = (LDA_);                                                          \
    const int t = threadIdx.x;                                                       \
    const int lane = t & 63;                                                         \
    const int wid = t >> 6;                                                          \
    const int lr = lane & 15;                                                        \
    const int kh = lane >> 4;                                                        \
    const int wrBase = (wid >> 1) * 64;                                              \
    const int wcBase = (wid & 1) * 64;                                               \
    const int nwg = gridDim.x * gridDim.y;                                           \
    const int flatid = blockIdx.y * gridDim.x + blockIdx.x;                          \
    const int swzid = (flatid & 7) * (nwg >> 3) + (flatid >> 3);                     \
    const int rowBase = (swzid / gridDim.x) * 128;                                   \
    const int colBase = (swzid % gridDim.x) * 128;                                   \
    f32x4 acc[4][4] = {};                                                            \
    const int r0 = t >> 2, c0 = (t & 3) ^ ((r0 >> 1) & 3);                           \
    const int s_hi = 256 + t;                                                        \
    const int r1 = s_hi >> 2, c1 = (s_hi & 3) ^ ((r1 >> 1) & 3);                     \
    const unsigned ldsOff0 = (unsigned)((t & 192) * 8);                              \
    const unsigned ldsOff1 = (unsigned)((256 + (t & 192)) * 8);                      \
    const int nt = (KLEN_) / BK;                                                     \
    GEMM_STAGE(0, 0);                                                                \
    GEMM_STAGE(1, BK);                                                               \
    int p = 0;                                                                       \
    for (int tt = 0; tt < nt; ++tt) {                                                \
        if (tt + 1 < nt) asm volatile("s_waitcnt vmcnt(4)" ::: "memory");            \
        else             asm volatile("s_waitcnt vmcnt(0)" ::: "memory");            \
        __builtin_amdgcn_s_barrier();                                                \
        __builtin_amdgcn_sched_barrier(0);                                           \
        if (tt + 2 < nt) {                                                           \
            int nb = p + 2; if (nb >= 3) nb -= 3;                                    \
            GEMM_STAGE(nb, (tt + 2) * BK);                                           \
        }                                                                            \
        f16x8 af[4], bfr[4];                                                         \
        _Pragma("unroll")                                                            \
        for (int mi = 0; mi < 4; ++mi) {                                             \
            const int ar = wrBase + mi * 16 + lr;                                    \
            const int ch = kh ^ ((ar >> 1) & 3);                                     \
            af[mi] = *(const f16x8*)&Asl[p][ar * BK + ch * 8];                       \
        }                                                                            \
        _Pragma("unroll")                                                            \
        for (int nj = 0; nj < 4; ++nj) {                                             \
            const int bc = wcBase + nj * 16 + lr;                                    \
            const int ch = kh ^ ((bc >> 1) & 3);                                     \
            bfr[nj] = *(const f16x8*)&Bsl[p][bc * BK + ch * 8];                      \
        }                                                                            \
        __builtin_amdgcn_s_setprio(1);                                               \
        _Pragma("unroll")                                                            \
        for (int mi = 0; mi < 4; ++mi)                                               \
            _Pragma("unroll")                                                        \
            for (int nj = 0; nj < 4; ++nj)                                           \
                acc[mi][nj] = __builtin_amdgcn_mfma_f32_16x16x32_f16(                \
                    af[mi], bfr[nj], acc[mi][nj], 0, 0, 0);                          \
        __builtin_amdgcn_s_setprio(0);                                               \
        p = (p == 2) ? 0 : p + 1;                                                    \
    }

// ---------------- generic GEMM: C[M,N] = A @ Bw^T + bias; CT=float|ushort(fp16) ----
template <int EPI, typename CT>
__global__ __launch_bounds__(256) void gemm_mfma_kernel(
    const unsigned short* __restrict__ A, const unsigned short* __restrict__ Bw,
    const float* __restrict__ bias, CT* __restrict__ C, int N, int K) {
    GEMM_BODY(A, Bw, K, K)
#pragma unroll
    for (int nj = 0; nj < 4; ++nj) {
        const int col = colBase + wcBase + nj * 16 + lr;
        const float bc = bias[col];
#pragma unroll
        for (int mi = 0; mi < 4; ++mi) {
            const int row = rowBase + wrBase + mi * 16 + kh * 4;
#pragma unroll
            for (int j = 0; j < 4; ++j) {
                float v = acc[mi][nj][j] + bc;
                if (EPI == 1) v = 0.5f * v * (1.0f + erff(v * 0.70710678118654752f));
                if constexpr (sizeof(CT) == 4) C[(size_t)(row + j) * N + col] = v;
                else                           C[(size_t)(row + j) * N + col] = f2h_u(v);
            }
        }
    }
}

// ------- split-K GEMM: part z -> (z < ZA ? CpA + z : CpB + z-ZA)[M][N] fp16 -------
__global__ __launch_bounds__(256) void gemm_splitk_kernel(
    const unsigned short* __restrict__ A, const unsigned short* __restrict__ Bw,
    unsigned short* __restrict__ CpA, unsigned short* __restrict__ CpB,
    int ZA, int N, int Kfull, int Kc) {
    const int z = blockIdx.z;
    GEMM_BODY(A + (size_t)z * Kc, Bw + (size_t)z * Kc, Kfull, Kc)
    unsigned short* Cp = (z < ZA) ? (CpA + (size_t)z * M * N)
                                  : (CpB + (size_t)(z - ZA) * M * N);
#pragma unroll
    for (int nj = 0; nj < 4; ++nj) {
        const int col = colBase + wcBase + nj * 16 + lr;
#pragma unroll
        for (int mi = 0; mi < 4; ++mi) {
            const int row = rowBase + wrBase + mi * 16 + kh * 4;
#pragma unroll
            for (int j = 0; j < 4; ++j)
                Cp[(size_t)(row + j) * N + col] = f2h_u(acc[mi][nj][j]);
        }
    }
}

// ---------------- QKV GEMM: q,k -> qkout [M][1536]; v -> vtout [BH][64][S] (V^T) ----
__global__ __launch_bounds__(256) void gemm_qkv_kernel(
    const unsigned short* __restrict__ A, const unsigned short* __restrict__ Bw,
    const float* __restrict__ bias, unsigned short* __restrict__ qkout,
    unsigned short* __restrict__ vtout) {
    GEMM_BODY(A, Bw, D, D)
    const bool isV = (colBase >= NQK);   // 128-aligned boundary -> block-uniform
#pragma unroll
    for (int nj = 0; nj < 4; ++nj) {
        const int col = colBase + wcBase + nj * 16 + lr;
        const float bc = bias[col];
        if (!isV) {
#pragma unroll
            for (int mi = 0; mi < 4; ++mi) {
                const int row = rowBase + wrBase + mi * 16 + kh * 4;
#pragma unroll
                for (int j = 0; j < 4; ++j)
                    qkout[(size_t)(row + j) * NQK + col] = f2h_u(acc[mi][nj][j] + bc);
            }
        } else {
            const int dd = col - NQK;
            const int h2 = dd >> 6, d6 = dd & 63;
#pragma unroll
            for (int mi = 0; mi < 4; ++mi) {
                const int row = rowBase + wrBase + mi * 16 + kh * 4;
                const int b2 = row >> 10, s2 = row & 1023;
                u16x4 ov;
#pragma unroll
                for (int j = 0; j < 4; ++j) ov[j] = f2h_u(acc[mi][nj][j] + bc);
                *(u16x4*)&vtout[(((size_t)(b2 * H + h2)) * 64 + d6) * S + s2] = ov;
            }
        }
    }
}

// ---------------- MFMA flash attention (double-buffered, 1 barrier/tile) ----------------
__global__ __launch_bounds__(256) void attention_kernel(
    const unsigned short* __restrict__ qk,   // [M][1536] fp16 (q|k)
    const unsigned short* __restrict__ vt,   // [BH][64][S] fp16 (V^T per head)
    unsigned short* __restrict__ o) {        // [M][768] fp16
    __shared__ unsigned short Qs[64 * 64];
    __shared__ unsigned short Ks[2][64 * 64];
    __shared__ unsigned short Vt[2][64 * 64];
    __shared__ _Float16 Ps[4][16 * 64];

    const int t = threadIdx.x;
    const int nwg = gridDim.x;                       // 768
    const int flatid = blockIdx.x;
    const int lin = (flatid & 7) * (nwg >> 3) + (flatid >> 3);
    const int qt = lin & 15;
    const int bh = lin >> 4;
    const int b = bh / H, hh = bh % H;
    const int w = t >> 6;
    const int lr = t & 15;
    const int kh = (t >> 4) & 3;

    const int r0 = t >> 3;
    const int g0 = (t & 7) ^ (r0 & 7);
    const unsigned lo0 = (unsigned)((t & 192) * 8);
    const unsigned lo1 = (unsigned)(2048 + (t & 192) * 8);

    const unsigned short* kgb = qk + D + hh * HD;
    const unsigned short* vgb = vt + (size_t)bh * 64 * S;

    {
        const size_t qrow0 = (size_t)(b * S + qt * 64);
        gload16(qk + (qrow0 + r0) * NQK + hh * HD + g0 * 8, &Qs[lo0]);
        gload16(qk + (qrow0 + r0 + 32) * NQK + hh * HD + g0 * 8, &Qs[lo1]);
        gload16(kgb + (size_t)(b * S + r0) * NQK + g0 * 8, &Ks[0][lo0]);
        gload16(kgb + (size_t)(b * S + r0 + 32) * NQK + g0 * 8, &Ks[0][lo1]);
        gload16(vgb + (size_t)r0 * S + g0 * 8, &Vt[0][lo0]);
        gload16(vgb + (size_t)(r0 + 32) * S + g0 * 8, &Vt[0][lo1]);
    }
    __syncthreads();

    float m_[4] = {-INFINITY, -INFINITY, -INFINITY, -INFINITY};
    float l_[4] = {};
    f32x4 oacc[4] = {};
    const int swlo = (kh)     ^ (lr & 7);
    const int swhi = (kh + 4) ^ (lr & 7);
    constexpr int NT = S / 64;

    for (int it = 0; it < NT; ++it) {
        const int cur = it & 1;
        if (it + 1 < NT) {
            const int kt = (it + 1) * 64;
            gload16(kgb + (size_t)(b * S + kt + r0) * NQK + g0 * 8, &Ks[cur ^ 1][lo0]);
            gload16(kgb + (size_t)(b * S + kt + r0 + 32) * NQK + g0 * 8, &Ks[cur ^ 1][lo1]);
            gload16(vgb + (size_t)r0 * S + kt + g0 * 8, &Vt[cur ^ 1][lo0]);
            gload16(vgb + (size_t)(r0 + 32) * S + kt + g0 * 8, &Vt[cur ^ 1][lo1]);
        }

        const int qr = w * 16 + lr;
        f16x8 aq0 = *(const f16x8*)&Qs[qr * 64 + swlo * 8];
        f16x8 aq1 = *(const f16x8*)&Qs[qr * 64 + swhi * 8];
        f32x4 sc[4];
        __builtin_amdgcn_s_setprio(1);
#pragma unroll
        for (int nj = 0; nj < 4; ++nj) {
            const int kr = nj * 16 + lr;
            f16x8 b0 = *(const f16x8*)&Ks[cur][kr * 64 + swlo * 8];
            f16x8 b1 = *(const f16x8*)&Ks[cur][kr * 64 + swhi * 8];
            f32x4 z = {};
            z = __builtin_amdgcn_mfma_f32_16x16x32_f16(aq0, b0, z, 0, 0, 0);
            z = __builtin_amdgcn_mfma_f32_16x16x32_f16(aq1, b1, z, 0, 0, 0);
            sc[nj] = z;
        }
        __builtin_amdgcn_s_setprio(0);

        float alpha[4];
#pragma unroll
        for (int j = 0; j < 4; ++j) {
            float rm = fmaxf(fmaxf(sc[0][j], sc[1][j]), fmaxf(sc[2][j], sc[3][j])) * 0.125f;
#pragma unroll
            for (int off = 1; off < 16; off <<= 1) rm = fmaxf(rm, __shfl_xor(rm, off, 64));
            const float mn = fmaxf(m_[j], rm);
            alpha[j] = __expf(m_[j] - mn);
            m_[j] = mn;
        }
        float ph[4][4];
        float rs[4] = {};
#pragma unroll
        for (int nj = 0; nj < 4; ++nj)
#pragma unroll
            for (int j = 0; j < 4; ++j) {
                float p2 = __expf(fmaf(sc[nj][j], 0.125f, -m_[j]));
                ph[nj][j] = p2;
                rs[j] += p2;
            }
#pragma unroll
        for (int j = 0; j < 4; ++j) {
#pragma unroll
            for (int off = 1; off < 16; off <<= 1) rs[j] += __shfl_xor(rs[j], off, 64);
            l_[j] = l_[j] * alpha[j] + rs[j];
        }
        _Float16* psw = &Ps[w][0];
#pragma unroll
        for (int nj = 0; nj < 4; ++nj)
#pragma unroll
            for (int j = 0; j < 4; ++j) {
                const int pr = kh * 4 + j;
                const int pc = nj * 16 + lr;
                psw[pr * 64 + (((pc >> 3) ^ (pr & 7)) * 8) + (pc & 7)] = (_Float16)ph[nj][j];
            }
#pragma unroll
        for (int nj = 0; nj < 4; ++nj)
#pragma unroll
            for (int j = 0; j < 4; ++j) oacc[nj][j] *= alpha[j];

        f16x8 pa0 = *(const f16x8*)&psw[lr * 64 + swlo * 8];
        f16x8 pa1 = *(const f16x8*)&psw[lr * 64 + swhi * 8];
        __builtin_amdgcn_s_setprio(1);
#pragma unroll
        for (int nj = 0; nj < 4; ++nj) {
            const int vr = nj * 16 + lr;
            f16x8 b0 = *(const f16x8*)&Vt[cur][vr * 64 + swlo * 8];
            f16x8 b1 = *(const f16x8*)&Vt[cur][vr * 64 + swhi * 8];
            oacc[nj] = __builtin_amdgcn_mfma_f32_16x16x32_f16(pa0, b0, oacc[nj], 0, 0, 0);
            oacc[nj] = __builtin_amdgcn_mfma_f32_16x16x32_f16(pa1, b1, oacc[nj], 0, 0, 0);
        }
        __builtin_amdgcn_s_setprio(0);

        __syncthreads();
    }

    float inv[4];
#pragma unroll
    for (int j = 0; j < 4; ++j) inv[j] = 1.0f / l_[j];
#pragma unroll
    for (int nj = 0; nj < 4; ++nj)
#pragma unroll
        for (int j = 0; j < 4; ++j) {
            const int token = b * S + qt * 64 + w * 16 + kh * 4 + j;
            o[(size_t)token * D + hh * HD + nj * 16 + lr] = f2h_u(oacc[nj][j] * inv[j]);
        }
}

// ---------------- pooler: split-K partial + reduce (fp16 h) ----------------
__global__ __launch_bounds__(768) void pooler_partial_kernel(
    const unsigned short* __restrict__ h, const float* __restrict__ Wp,
    float* __restrict__ partial) {
    const int slice = blockIdx.x;
    const int b = blockIdx.y;
    const int d = threadIdx.x;
    const unsigned short* hrow = h + (size_t)b * S * D + slice * 48;
    const float* wcol = Wp + (size_t)slice * 48 * D + d;
    float acc = 0.f;
#pragma unroll
    for (int kk = 0; kk < 48; ++kk) acc = fmaf(h2f(hrow[kk]), wcol[(size_t)kk * D], acc);
    partial[((size_t)b * 16 + slice) * D + d] = acc;
}

__global__ __launch_bounds__(768) void pooler_reduce_kernel(
    const float* __restrict__ partial, const float* __restrict__ bp,
    float* __restrict__ out) {
    const int b = blockIdx.x;
    const int d = threadIdx.x;
    float acc = bp[d];
#pragma unroll
    for (int s2 = 0; s2 < 16; ++s2) acc += partial[((size_t)b * 16 + s2) * D + d];
    out[(size_t)b * D + d] = tanhf(acc);
}

}  // namespace

extern "C" void kernel_launch(void* const* d_in, const int* in_sizes, int n_in,
                              void* d_out, int out_size, void* d_ws, size_t ws_size,
                              hipStream_t stream) {
    (void)in_sizes; (void)n_in; (void)out_size; (void)ws_size;

    const int*   x     = (const int*)  d_in[0];
    const float* we    = (const float*)d_in[1];
    const float* pe    = (const float*)d_in[2];
    const float* te    = (const float*)d_in[3];
    const float* emb_g = (const float*)d_in[4];
    const float* emb_b = (const float*)d_in[5];
    const float* Wq    = (const float*)d_in[6];
    const float* bq    = (const float*)d_in[7];
    const float* Wk    = (const float*)d_in[8];
    const float* bk    = (const float*)d_in[9];
    const float* Wv    = (const float*)d_in[10];
    const float* bv    = (const float*)d_in[11];
    const float* Wo    = (const float*)d_in[12];
    const float* bo    = (const float*)d_in[13];
    const float* ln1_g = (const float*)d_in[14];
    const float* ln1_b = (const float*)d_in[15];
    const float* W1    = (const float*)d_in[16];
    const float* b1    = (const float*)d_in[17];
    const float* W2    = (const float*)d_in[18];
    const float* b2    = (const float*)d_in[19];
    const float* ln2_g = (const float*)d_in[20];
    const float* ln2_b = (const float*)d_in[21];
    const float* Wp    = (const float*)d_in[22];
    const float* bp    = (const float*)d_in[23];

    // workspace (~101 MB): fp16 stream only
    char* wp8 = (char*)d_ws;
    unsigned short* h_f16  = (unsigned short*)wp8;     wp8 += (size_t)M * D * 2;
    unsigned short* blockA = (unsigned short*)wp8;     wp8 += (size_t)M * F * 2;
    unsigned short* qk_f   = blockA;                         // M*1536
    unsigned short* v_t    = blockA + (size_t)M * NQK;       // 48*64*1024
    unsigned short* attno  = v_t + (size_t)B * H * 64 * S;   // M*768
    unsigned short* inter  = blockA;                         // M*F (aliases all three)
    unsigned short* wo_part = blockA;                        // 3 x M*D fp16 (qk+v_t dead)
    char*           oproj8 = wp8;                      wp8 += (size_t)M * D * 4;
    unsigned short* f2_part = (unsigned short*)oproj8;       // 2 x M*D fp16
    unsigned short* Wqkv_t = (unsigned short*)wp8;     wp8 += (size_t)L * NQKV * D * 2;
    unsigned short* Wo_t   = (unsigned short*)wp8;     wp8 += (size_t)L * D * D * 2;
    unsigned short* W1_t   = (unsigned short*)wp8;     wp8 += (size_t)L * F * D * 2;
    unsigned short* W2_t   = (unsigned short*)wp8;     wp8 += (size_t)L * D * F * 2;
    float*          bqkv   = (float*)wp8;              wp8 += (size_t)L * NQKV * 4;
    float*          ppart  = (float*)wp8;                    // 4*16*768 fp32

    // fused weight prep: 1728 pipelined 64x256 chunks + 36 bias blocks
    weight_prep_kernel<<<1764, 256, 0, stream>>>(
        Wq, Wk, Wv, Wo, W1, W2, bq, bk, bv, Wqkv_t, Wo_t, W1_t, W2_t, bqkv);

    embed_ln_kernel<<<M, 192, 0, stream>>>(x, we, pe, te, emb_g, emb_b, h_f16);

    for (int l = 0; l < L; ++l) {
        gemm_qkv_kernel<<<dim3(NQKV / 128, M / 128), 256, 0, stream>>>(
            h_f16, Wqkv_t + (size_t)l * NQKV * D, bqkv + l * NQKV, qk_f, v_t);

        attention_kernel<<<(S / 64) * B * H, 256, 0, stream>>>(qk_f, v_t, attno);

        // O-proj: split-K=3 (K=768 -> 3x256), fp16 partials into dead qk|v region
        gemm_splitk_kernel<<<dim3(D / 128, M / 128, 3), 256, 0, stream>>>(
            attno, Wo_t + (size_t)l * D * D, wo_part, nullptr, 3, D, D, 256);
        ln_reduce_kernel<3, 0, false, true><<<M, 192, 0, stream>>>(
            wo_part, nullptr, bo + l * D, h_f16, ln1_g + l * D, ln1_b + l * D, h_f16);

        gemm_mfma_kernel<1, unsigned short><<<dim3(F / 128, M / 128), 256, 0, stream>>>(
            h_f16, W1_t + (size_t)l * F * D, b1 + l * F, inter, F, D);

        // FFN2: split-K=3; parts 0,1 in oproj region, part 2 in dead h_f16
        gemm_splitk_kernel<<<dim3(D / 128, M / 128, 3), 256, 0, stream>>>(
            inter, W2_t + (size_t)l * D * F, f2_part, h_f16, 2, D, F, 1024);
        ln_reduce_kernel<2, 1, true, false><<<M, 192, 0, stream>>>(
            f2_part, h_f16, b2 + l * D, nullptr, ln2_g + l * D, ln2_b + l * D, h_f16);
    }

    pooler_partial_kernel<<<dim3(16, B), 768, 0, stream>>>(h_f16, Wp, ppart);
    pooler_reduce_kernel<<<B, 768, 0, stream>>>(ppart, bp, (float*)d_out);
}

// Round 17
// 694.670 us; speedup vs baseline: 1.0065x; 1.0065x over previous
//
#include <hip/hip_runtime.h>
#include <math.h>

namespace {

constexpr int B  = 4;
constexpr int S  = 1024;
constexpr int D  = 768;
constexpr int H  = 12;
constexpr int HD = 64;
constexpr int F  = 3072;
constexpr int L  = 4;
constexpr int M  = B * S;       // 4096 tokens
constexpr int NQKV = 3 * D;     // 2304
constexpr int NQK = 2 * D;      // 1536 (q|k packed)

typedef __attribute__((ext_vector_type(4))) float    f32x4;
typedef _Float16 f16x8 __attribute__((ext_vector_type(8)));
typedef __attribute__((ext_vector_type(8))) unsigned short u16x8;
typedef __attribute__((ext_vector_type(4))) unsigned short u16x4;

__device__ __forceinline__ unsigned short f2h_u(float f) {
    _Float16 h = (_Float16)f;
    return __builtin_bit_cast(unsigned short, h);
}
__device__ __forceinline__ float h2f(unsigned short u) {
    return (float)__builtin_bit_cast(_Float16, u);
}

__device__ __forceinline__ void gload16(const void* gptr, void* ldsptr) {
    __builtin_amdgcn_global_load_lds(
        (const __attribute__((address_space(1))) unsigned int*)gptr,
        (__attribute__((address_space(3))) unsigned int*)ldsptr,
        16, 0, 0);
}

// ---------------- reductions ----------------
__device__ __forceinline__ float wave_sum(float v) {
#pragma unroll
    for (int off = 32; off; off >>= 1) v += __shfl_xor(v, off, 64);
    return v;
}
// 192-thread (3-wave) block reduce
__device__ __forceinline__ float block_sum192(float v, float* sm) {
    v = wave_sum(v);
    __syncthreads();
    if ((threadIdx.x & 63) == 0) sm[threadIdx.x >> 6] = v;
    __syncthreads();
    return sm[0] + sm[1] + sm[2];
}

// ---------------- fused weight prep: 64x64 tiles ----------------
// NOTE (rounds 14-16): three optimization attempts on this kernel (32x32 grid
// variant, 64x64 tiles, pipelined 64x256 stripes) all measured neutral at
// ~54-56 us; mechanism of its ~50%-of-BW ceiling remains unidentified. Keep
// the simplest 64x64 form.
__device__ __forceinline__ void transpose_tile64(const float* __restrict__ src,
                                                 unsigned short* __restrict__ dst,
                                                 int R, int C, int rb, int cb) {
    __shared__ float tile[64][65];
    const int t = threadIdx.x;
    const int r = t >> 2;
    const int q4 = t & 3;
#pragma unroll
    for (int k = 0; k < 4; ++k) {
        const int cq = (q4 + k * 4) * 4;
        const float4 v = *(const float4*)&src[(size_t)(rb + r) * C + cb + cq];
        tile[r][cq + 0] = v.x; tile[r][cq + 1] = v.y;
        tile[r][cq + 2] = v.z; tile[r][cq + 3] = v.w;
    }
    __syncthreads();
    const int dc = t >> 2;
    const int s8 = t & 3;
#pragma unroll
    for (int k = 0; k < 2; ++k) {
        const int rq = (s8 + k * 4) * 8;
        u16x8 o;
#pragma unroll
        for (int j = 0; j < 8; ++j) o[j] = f2h_u(tile[rq + j][dc]);
        *(u16x8*)&dst[(size_t)(cb + dc) * R + rb + rq] = o;
    }
}

__global__ __launch_bounds__(256) void weight_prep_kernel(
    const float* __restrict__ Wq, const float* __restrict__ Wk,
    const float* __restrict__ Wv, const float* __restrict__ Wo,
    const float* __restrict__ W1, const float* __restrict__ W2,
    const float* __restrict__ bq, const float* __restrict__ bk,
    const float* __restrict__ bv,
    unsigned short* __restrict__ Wqkv_t, unsigned short* __restrict__ Wo_t,
    unsigned short* __restrict__ W1_t, unsigned short* __restrict__ W2_t,
    float* __restrict__ bqkv) {
    const int tid = blockIdx.x;
    if (tid < 2304) {                        // Wq/Wk/Wv/Wo : DxD, 144 tiles each
        const int w = tid / 144, rem = tid % 144;
        const int l = w >> 2, which = w & 3;
        const float* src = (which == 0 ? Wq : which == 1 ? Wk : which == 2 ? Wv : Wo)
                           + (size_t)l * D * D;
        unsigned short* dst = (which < 3)
            ? Wqkv_t + ((size_t)l * NQKV + which * D) * D
            : Wo_t + (size_t)l * D * D;
        transpose_tile64(src, dst, D, D, (rem / 12) * 64, (rem % 12) * 64);
    } else if (tid < 4608) {                 // W1 : R=D, C=F -> [F][D], 576 tiles/l
        const int t2 = tid - 2304, l = t2 / 576, rem = t2 % 576;
        transpose_tile64(W1 + (size_t)l * D * F, W1_t + (size_t)l * F * D,
                         D, F, (rem / 48) * 64, (rem % 48) * 64);
    } else if (tid < 6912) {                 // W2 : R=F, C=D -> [D][F], 576 tiles/l
        const int t2 = tid - 4608, l = t2 / 576, rem = t2 % 576;
        transpose_tile64(W2 + (size_t)l * F * D, W2_t + (size_t)l * D * F,
                         F, D, (rem / 12) * 64, (rem % 12) * 64);
    } else {                                 // bias concat (36 blocks)
        const int i = (tid - 6912) * 256 + threadIdx.x;
        if (i < L * NQKV) {
            const int l = i / NQKV, j = i % NQKV;
            bqkv[i] = (j < D) ? bq[l * D + j]
                    : (j < 2 * D) ? bk[l * D + j - D] : bv[l * D + j - 2 * D];
        }
    }
}

// ---------------- embeddings + LayerNorm -> fp16 stream (192 thr) ------
__global__ __launch_bounds__(192) void embed_ln_kernel(
    const int* __restrict__ x, const float* __restrict__ we,
    const float* __restrict__ pe, const float* __restrict__ te,
    const float* __restrict__ g, const float* __restrict__ bb,
    unsigned short* __restrict__ hh) {
    __shared__ float sm[3];
    const int row = blockIdx.x;
    const int s = row & (S - 1);
    const int tok = x[row];
    const int t = threadIdx.x;
    const int d = t * 4;
    float v[4];
    const float4 w = *(const float4*)&we[(size_t)tok * D + d];
    const float4 p = *(const float4*)&pe[(size_t)s * D + d];
    const float4 tt = *(const float4*)&te[d];
    v[0] = w.x + p.x + tt.x; v[1] = w.y + p.y + tt.y;
    v[2] = w.z + p.z + tt.z; v[3] = w.w + p.w + tt.w;
    const float mu = block_sum192(v[0] + v[1] + v[2] + v[3], sm) * (1.0f / D);
    float lvar = 0.f;
#pragma unroll
    for (int i = 0; i < 4; ++i) { float dv = v[i] - mu; lvar += dv * dv; }
    const float var = block_sum192(lvar, sm) * (1.0f / D);
    const float inv = rsqrtf(var + 1e-12f);
    const float4 g4 = *(const float4*)&g[d];
    const float4 b4 = *(const float4*)&bb[d];
    u16x4 ob;
    ob[0] = f2h_u((v[0] - mu) * inv * g4.x + b4.x);
    ob[1] = f2h_u((v[1] - mu) * inv * g4.y + b4.y);
    ob[2] = f2h_u((v[2] - mu) * inv * g4.z + b4.z);
    ob[3] = f2h_u((v[3] - mu) * inv * g4.w + b4.w);
    *(u16x4*)&hh[(size_t)row * D + d] = ob;
}

// ------- partial-sum reduce + (opt GELU / fp16 residual) + LayerNorm (192 thr) -----
// Row-local in-place safe: all row reads (parts, res) complete before the first
// reduction barrier; the write happens after. outh may alias res or a pB part.
template <int NPA, int NPB, bool GELU_, bool HAS_RES>
__global__ __launch_bounds__(192) void ln_reduce_kernel(
    const unsigned short* __restrict__ pA,      // NPA x [M][D] fp16 (contiguous)
    const unsigned short* __restrict__ pB,      // NPB x [M][D] fp16 (contiguous) or null
    const float* __restrict__ bias,             // [D]
    const unsigned short* __restrict__ res,     // [M][D] fp16 or nullptr
    const float* __restrict__ g, const float* __restrict__ bb,
    unsigned short* __restrict__ outh) {
    __shared__ float sm[3];
    const int row = blockIdx.x;
    const int t = threadIdx.x;
    const int d = t * 4;
    float v[4];
    const float4 bi = *(const float4*)&bias[d];
    v[0] = bi.x; v[1] = bi.y; v[2] = bi.z; v[3] = bi.w;
#pragma unroll
    for (int pp = 0; pp < NPA; ++pp) {
        const u16x4 pu = *(const u16x4*)&pA[(size_t)pp * M * D + (size_t)row * D + d];
#pragma unroll
        for (int i = 0; i < 4; ++i) v[i] += h2f(pu[i]);
    }
#pragma unroll
    for (int pp = 0; pp < NPB; ++pp) {
        const u16x4 pu = *(const u16x4*)&pB[(size_t)pp * M * D + (size_t)row * D + d];
#pragma unroll
        for (int i = 0; i < 4; ++i) v[i] += h2f(pu[i]);
    }
    if (HAS_RES) {
        const u16x4 rv = *(const u16x4*)&res[(size_t)row * D + d];
#pragma unroll
        for (int i = 0; i < 4; ++i) v[i] += h2f(rv[i]);
    }
    if (GELU_) {
#pragma unroll
        for (int i = 0; i < 4; ++i)
            v[i] = 0.5f * v[i] * (1.0f + erff(v[i] * 0.70710678118654752f));
    }
    const float mu = block_sum192(v[0] + v[1] + v[2] + v[3], sm) * (1.0f / D);
    float lvar = 0.f;
#pragma unroll
    for (int i = 0; i < 4; ++i) { float dv = v[i] - mu; lvar += dv * dv; }
    const float var = block_sum192(lvar, sm) * (1.0f / D);
    const float inv = rsqrtf(var + 1e-12f);
    const float4 g4 = *(const float4*)&g[d];
    const float4 b4 = *(const float4*)&bb[d];
    u16x4 ob;
    ob[0] = f2h_u((v[0] - mu) * inv * g4.x + b4.x);
    ob[1] = f2h_u((v[1] - mu) * inv * g4.y + b4.y);
    ob[2] = f2h_u((v[2] - mu) * inv * g4.z + b4.z);
    ob[3] = f2h_u((v[3] - mu) * inv * g4.w + b4.w);
    *(u16x4*)&outh[(size_t)row * D + d] = ob;
}

// ======== shared fp16 MFMA GEMM body: 128x128 tile, BK=32, 4 waves ========
// 3-buffer pipeline, counted vmcnt(4); T1 XCD-swizzled block ids; T5 setprio.
// 48 KB LDS -> 3 blocks/CU (proven optimum: 72 KB/2-blk was -45%, 32 KB/5-blk neutral).
#define GEMM_STAGE(buf, k0)                                                          \
    do {                                                                             \
        gload16(Ab + (size_t)(rowBase + r0) * LDA + (k0) + c0 * 8, &Asl[buf][ldsOff0]); \
        gload16(Ab + (size_t)(rowBase + r1) * LDA + (k0) + c1 * 8, &Asl[buf][ldsOff1]); \
        gload16(Bb + (size_t)(colBase + r0) * LDA + (k0) + c0 * 8, &Bsl[buf][ldsOff0]); \
        gload16(Bb + (size_t)(colBase + r1) * LDA + (k0) + c1 * 8, &Bsl[buf][ldsOff1]); \
    } while (0)

#define GEMM_BODY(A_, Bw_, LDA_, KLEN_)                                              \
    constexpr int BK = 32;                                                           \
    __shared__ unsigned short Asl[3][128 * BK];                                      \
    __shared__ unsigned short Bsl[3][128 * BK];                                      \
    const unsigned short* Ab = (A_);                                                 \
    const unsigned short* Bb = (Bw_);                                                \
    const int LDA = (LDA_);                                                          \
    const int t = threadIdx.x;                                                       \
    const int lane = t & 63;                                                         \
    const int wid = t >> 6;                                                          \
    const int lr = lane & 15;                                                        \
    const int kh = lane >> 4;                                                        \
    const int wrBase = (wid >> 1) * 64;                                              \
    const int wcBase = (wid & 1) * 64;                                               \
    const int nwg = gridDim.x * gridDim.y;                                           \
    const int flatid = blockIdx.y * gridDim.x + blockIdx.x;                          \
    const int swzid = (flatid & 7) * (nwg >> 3) + (flatid >> 3);                     \
    const int rowBase = (swzid / gridDim.x) * 128;                                   \
    const int colBase = (swzid % gridDim.x) * 128;                                   \
    f32x4 acc[4][4] = {};                                                            \
    const int r0 = t >> 2, c0 = (t & 3) ^ ((r0 >> 1) & 3);                           \
    const int s_hi = 256 + t;                                                        \
    const int r1 = s_hi >> 2, c1 = (s_hi & 3) ^ ((r1 >> 1) & 3);                     \
    const unsigned ldsOff0 = (unsigned)((t & 192) * 8);                              \
    const unsigned ldsOff1 = (unsigned)((256 + (t & 192)) * 8);                      \
    const int nt = (KLEN_) / BK;                                                     \
    GEMM_STAGE(0, 0);                                                                \
    GEMM_STAGE(1, BK);                                                               \
    int p = 0;                                                                       \
    for (int tt = 0; tt < nt; ++tt) {                                                \
        if (tt + 1 < nt) asm volatile("s_waitcnt vmcnt(4)" ::: "memory");            \
        else             asm volatile("s_waitcnt vmcnt(0)" ::: "memory");            \
        __builtin_amdgcn_s_barrier();                                                \
        __builtin_amdgcn_sched_barrier(0);                                           \
        if (tt + 2 < nt) {                                                           \
            int nb = p + 2; if (nb >= 3) nb -= 3;                                    \
            GEMM_STAGE(nb, (tt + 2) * BK);                                           \
        }                                                                            \
        f16x8 af[4], bfr[4];                                                         \
        _Pragma("unroll")                                                            \
        for (int mi = 0; mi < 4; ++mi) {                                             \
            const int ar = wrBase + mi * 16 + lr;                                    \
            const int ch = kh ^ ((ar >> 1) & 3);                                     \
            af[mi] = *(const f16x8*)&Asl[p][ar * BK + ch * 8];                       \
        }                                                                            \
        _Pragma("unroll")                                                            \
        for (int nj = 0; nj < 4; ++nj) {                                             \
            const int bc = wcBase + nj * 16 + lr;                                    \
            const int ch = kh ^ ((bc >> 1) & 3);                                     \
            bfr[nj] = *(const f16x8*)&Bsl[p][bc * BK + ch * 8];                      \
        }                                                                            \
        __builtin_amdgcn_s_setprio(1);                                               \
        _Pragma("unroll")                                                            \
        for (int mi = 0; mi < 4; ++mi)                                               \
            _Pragma("unroll")                                                        \
            for (int nj = 0; nj < 4; ++nj)                                           \
                acc[mi][nj] = __builtin_amdgcn_mfma_f32_16x16x32_f16(                \
                    af[mi], bfr[nj], acc[mi][nj], 0, 0, 0);                          \
        __builtin_amdgcn_s_setprio(0);                                               \
        p = (p == 2) ? 0 : p + 1;                                                    \
    }

// ---------------- generic GEMM: C[M,N] = A @ Bw^T + bias; CT=float|ushort(fp16) ----
template <int EPI, typename CT>
__global__ __launch_bounds__(256) void gemm_mfma_kernel(
    const unsigned short* __restrict__ A, const unsigned short* __restrict__ Bw,
    const float* __restrict__ bias, CT* __restrict__ C, int N, int K) {
    GEMM_BODY(A, Bw, K, K)
#pragma unroll
    for (int nj = 0; nj < 4; ++nj) {
        const int col = colBase + wcBase + nj * 16 + lr;
        const float bc = bias[col];
#pragma unroll
        for (int mi = 0; mi < 4; ++mi) {
            const int row = rowBase + wrBase + mi * 16 + kh * 4;
#pragma unroll
            for (int j = 0; j < 4; ++j) {
                float v = acc[mi][nj][j] + bc;
                if (EPI == 1) v = 0.5f * v * (1.0f + erff(v * 0.70710678118654752f));
                if constexpr (sizeof(CT) == 4) C[(size_t)(row + j) * N + col] = v;
                else                           C[(size_t)(row + j) * N + col] = f2h_u(v);
            }
        }
    }
}

// ------- split-K GEMM: part z -> (z < ZA ? CpA + z : CpB + z-ZA)[M][N] fp16 -------
__global__ __launch_bounds__(256) void gemm_splitk_kernel(
    const unsigned short* __restrict__ A, const unsigned short* __restrict__ Bw,
    unsigned short* __restrict__ CpA, unsigned short* __restrict__ CpB,
    int ZA, int N, int Kfull, int Kc) {
    const int z = blockIdx.z;
    GEMM_BODY(A + (size_t)z * Kc, Bw + (size_t)z * Kc, Kfull, Kc)
    unsigned short* Cp = (z < ZA) ? (CpA + (size_t)z * M * N)
                                  : (CpB + (size_t)(z - ZA) * M * N);
#pragma unroll
    for (int nj = 0; nj < 4; ++nj) {
        const int col = colBase + wcBase + nj * 16 + lr;
#pragma unroll
        for (int mi = 0; mi < 4; ++mi) {
            const int row = rowBase + wrBase + mi * 16 + kh * 4;
#pragma unroll
            for (int j = 0; j < 4; ++j)
                Cp[(size_t)(row + j) * N + col] = f2h_u(acc[mi][nj][j]);
        }
    }
}

// ---------------- QKV GEMM: q,k -> qkout [M][1536]; v -> vtout [BH][64][S] (V^T) ----
__global__ __launch_bounds__(256) void gemm_qkv_kernel(
    const unsigned short* __restrict__ A, const unsigned short* __restrict__ Bw,
    const float* __restrict__ bias, unsigned short* __restrict__ qkout,
    unsigned short* __restrict__ vtout) {
    GEMM_BODY(A, Bw, D, D)
    const bool isV = (colBase >= NQK);   // 128-aligned boundary -> block-uniform
#pragma unroll
    for (int nj = 0; nj < 4; ++nj) {
        const int col = colBase + wcBase + nj * 16 + lr;
        const float bc = bias[col];
        if (!isV) {
#pragma unroll
            for (int mi = 0; mi < 4; ++mi) {
                const int row = rowBase + wrBase + mi * 16 + kh * 4;
#pragma unroll
                for (int j = 0; j < 4; ++j)
                    qkout[(size_t)(row + j) * NQK + col] = f2h_u(acc[mi][nj][j] + bc);
            }
        } else {
            const int dd = col - NQK;
            const int h2 = dd >> 6, d6 = dd & 63;
#pragma unroll
            for (int mi = 0; mi < 4; ++mi) {
                const int row = rowBase + wrBase + mi * 16 + kh * 4;
                const int b2 = row >> 10, s2 = row & 1023;
                u16x4 ov;
#pragma unroll
                for (int j = 0; j < 4; ++j) ov[j] = f2h_u(acc[mi][nj][j] + bc);
                *(u16x4*)&vtout[(((size_t)(b2 * H + h2)) * 64 + d6) * S + s2] = ov;
            }
        }
    }
}

// ---------------- MFMA flash attention (double-buffered, 1 barrier/tile) ----------------
// 1-D grid (768 blocks) with XCD swizzle: the 16 q-tile blocks sharing one (b,h)'s
// K/V are consecutive post-swizzle -> same XCD L2.
__global__ __launch_bounds__(256) void attention_kernel(
    const unsigned short* __restrict__ qk,   // [M][1536] fp16 (q|k)
    const unsigned short* __restrict__ vt,   // [BH][64][S] fp16 (V^T per head)
    unsigned short* __restrict__ o) {        // [M][768] fp16
    __shared__ unsigned short Qs[64 * 64];
    __shared__ unsigned short Ks[2][64 * 64];
    __shared__ unsigned short Vt[2][64 * 64];
    __shared__ _Float16 Ps[4][16 * 64];

    const int t = threadIdx.x;
    const int nwg = gridDim.x;                       // 768
    const int flatid = blockIdx.x;
    const int lin = (flatid & 7) * (nwg >> 3) + (flatid >> 3);
    const int qt = lin & 15;
    const int bh = lin >> 4;
    const int b = bh / H, hh = bh % H;
    const int w = t >> 6;
    const int lr = t & 15;
    const int kh = (t >> 4) & 3;

    const int r0 = t >> 3;
    const int g0 = (t & 7) ^ (r0 & 7);
    const unsigned lo0 = (unsigned)((t & 192) * 8);
    const unsigned lo1 = (unsigned)(2048 + (t & 192) * 8);

    const unsigned short* kgb = qk + D + hh * HD;
    const unsigned short* vgb = vt + (size_t)bh * 64 * S;

    {
        const size_t qrow0 = (size_t)(b * S + qt * 64);
        gload16(qk + (qrow0 + r0) * NQK + hh * HD + g0 * 8, &Qs[lo0]);
        gload16(qk + (qrow0 + r0 + 32) * NQK + hh * HD + g0 * 8, &Qs[lo1]);
        gload16(kgb + (size_t)(b * S + r0) * NQK + g0 * 8, &Ks[0][lo0]);
        gload16(kgb + (size_t)(b * S + r0 + 32) * NQK + g0 * 8, &Ks[0][lo1]);
        gload16(vgb + (size_t)r0 * S + g0 * 8, &Vt[0][lo0]);
        gload16(vgb + (size_t)(r0 + 32) * S + g0 * 8, &Vt[0][lo1]);
    }
    __syncthreads();

    float m_[4] = {-INFINITY, -INFINITY, -INFINITY, -INFINITY};
    float l_[4] = {};
    f32x4 oacc[4] = {};
    const int swlo = (kh)     ^ (lr & 7);
    const int swhi = (kh + 4) ^ (lr & 7);
    constexpr int NT = S / 64;

    for (int it = 0; it < NT; ++it) {
        const int cur = it & 1;
        if (it + 1 < NT) {
            const int kt = (it + 1) * 64;
            gload16(kgb + (size_t)(b * S + kt + r0) * NQK + g0 * 8, &Ks[cur ^ 1][lo0]);
            gload16(kgb + (size_t)(b * S + kt + r0 + 32) * NQK + g0 * 8, &Ks[cur ^ 1][lo1]);
            gload16(vgb + (size_t)r0 * S + kt + g0 * 8, &Vt[cur ^ 1][lo0]);
            gload16(vgb + (size_t)(r0 + 32) * S + kt + g0 * 8, &Vt[cur ^ 1][lo1]);
        }

        const int qr = w * 16 + lr;
        f16x8 aq0 = *(const f16x8*)&Qs[qr * 64 + swlo * 8];
        f16x8 aq1 = *(const f16x8*)&Qs[qr * 64 + swhi * 8];
        f32x4 sc[4];
        __builtin_amdgcn_s_setprio(1);
#pragma unroll
        for (int nj = 0; nj < 4; ++nj) {
            const int kr = nj * 16 + lr;
            f16x8 b0 = *(const f16x8*)&Ks[cur][kr * 64 + swlo * 8];
            f16x8 b1 = *(const f16x8*)&Ks[cur][kr * 64 + swhi * 8];
            f32x4 z = {};
            z = __builtin_amdgcn_mfma_f32_16x16x32_f16(aq0, b0, z, 0, 0, 0);
            z = __builtin_amdgcn_mfma_f32_16x16x32_f16(aq1, b1, z, 0, 0, 0);
            sc[nj] = z;
        }
        __builtin_amdgcn_s_setprio(0);

        float alpha[4];
#pragma unroll
        for (int j = 0; j < 4; ++j) {
            float rm = fmaxf(fmaxf(sc[0][j], sc[1][j]), fmaxf(sc[2][j], sc[3][j])) * 0.125f;
#pragma unroll
            for (int off = 1; off < 16; off <<= 1) rm = fmaxf(rm, __shfl_xor(rm, off, 64));
            const float mn = fmaxf(m_[j], rm);
            alpha[j] = __expf(m_[j] - mn);
            m_[j] = mn;
        }
        float ph[4][4];
        float rs[4] = {};
#pragma unroll
        for (int nj = 0; nj < 4; ++nj)
#pragma unroll
            for (int j = 0; j < 4; ++j) {
                float p2 = __expf(fmaf(sc[nj][j], 0.125f, -m_[j]));
                ph[nj][j] = p2;
                rs[j] += p2;
            }
#pragma unroll
        for (int j = 0; j < 4; ++j) {
#pragma unroll
            for (int off = 1; off < 16; off <<= 1) rs[j] += __shfl_xor(rs[j], off, 64);
            l_[j] = l_[j] * alpha[j] + rs[j];
        }
        _Float16* psw = &Ps[w][0];
#pragma unroll
        for (int nj = 0; nj < 4; ++nj)
#pragma unroll
            for (int j = 0; j < 4; ++j) {
                const int pr = kh * 4 + j;
                const int pc = nj * 16 + lr;
                psw[pr * 64 + (((pc >> 3) ^ (pr & 7)) * 8) + (pc & 7)] = (_Float16)ph[nj][j];
            }
#pragma unroll
        for (int nj = 0; nj < 4; ++nj)
#pragma unroll
            for (int j = 0; j < 4; ++j) oacc[nj][j] *= alpha[j];

        f16x8 pa0 = *(const f16x8*)&psw[lr * 64 + swlo * 8];
        f16x8 pa1 = *(const f16x8*)&psw[lr * 64 + swhi * 8];
        __builtin_amdgcn_s_setprio(1);
#pragma unroll
        for (int nj = 0; nj < 4; ++nj) {
            const int vr = nj * 16 + lr;
            f16x8 b0 = *(const f16x8*)&Vt[cur][vr * 64 + swlo * 8];
            f16x8 b1 = *(const f16x8*)&Vt[cur][vr * 64 + swhi * 8];
            oacc[nj] = __builtin_amdgcn_mfma_f32_16x16x32_f16(pa0, b0, oacc[nj], 0, 0, 0);
            oacc[nj] = __builtin_amdgcn_mfma_f32_16x16x32_f16(pa1, b1, oacc[nj], 0, 0, 0);
        }
        __builtin_amdgcn_s_setprio(0);

        __syncthreads();
    }

    float inv[4];
#pragma unroll
    for (int j = 0; j < 4; ++j) inv[j] = 1.0f / l_[j];
#pragma unroll
    for (int nj = 0; nj < 4; ++nj)
#pragma unroll
        for (int j = 0; j < 4; ++j) {
            const int token = b * S + qt * 64 + w * 16 + kh * 4 + j;
            o[(size_t)token * D + hh * HD + nj * 16 + lr] = f2h_u(oacc[nj][j] * inv[j]);
        }
}

// ---------------- pooler: split-K partial + reduce (fp16 h) ----------------
__global__ __launch_bounds__(768) void pooler_partial_kernel(
    const unsigned short* __restrict__ h, const float* __restrict__ Wp,
    float* __restrict__ partial) {
    const int slice = blockIdx.x;
    const int b = blockIdx.y;
    const int d = threadIdx.x;
    const unsigned short* hrow = h + (size_t)b * S * D + slice * 48;
    const float* wcol = Wp + (size_t)slice * 48 * D + d;
    float acc = 0.f;
#pragma unroll
    for (int kk = 0; kk < 48; ++kk) acc = fmaf(h2f(hrow[kk]), wcol[(size_t)kk * D], acc);
    partial[((size_t)b * 16 + slice) * D + d] = acc;
}

__global__ __launch_bounds__(768) void pooler_reduce_kernel(
    const float* __restrict__ partial, const float* __restrict__ bp,
    float* __restrict__ out) {
    const int b = blockIdx.x;
    const int d = threadIdx.x;
    float acc = bp[d];
#pragma unroll
    for (int s2 = 0; s2 < 16; ++s2) acc += partial[((size_t)b * 16 + s2) * D + d];
    out[(size_t)b * D + d] = tanhf(acc);
}

}  // namespace

extern "C" void kernel_launch(void* const* d_in, const int* in_sizes, int n_in,
                              void* d_out, int out_size, void* d_ws, size_t ws_size,
                              hipStream_t stream) {
    (void)in_sizes; (void)n_in; (void)out_size; (void)ws_size;

    const int*   x     = (const int*)  d_in[0];
    const float* we    = (const float*)d_in[1];
    const float* pe    = (const float*)d_in[2];
    const float* te    = (const float*)d_in[3];
    const float* emb_g = (const float*)d_in[4];
    const float* emb_b = (const float*)d_in[5];
    const float* Wq    = (const float*)d_in[6];
    const float* bq    = (const float*)d_in[7];
    const float* Wk    = (const float*)d_in[8];
    const float* bk    = (const float*)d_in[9];
    const float* Wv    = (const float*)d_in[10];
    const float* bv    = (const float*)d_in[11];
    const float* Wo    = (const float*)d_in[12];
    const float* bo    = (const float*)d_in[13];
    const float* ln1_g = (const float*)d_in[14];
    const float* ln1_b = (const float*)d_in[15];
    const float* W1    = (const float*)d_in[16];
    const float* b1    = (const float*)d_in[17];
    const float* W2    = (const float*)d_in[18];
    const float* b2    = (const float*)d_in[19];
    const float* ln2_g = (const float*)d_in[20];
    const float* ln2_b = (const float*)d_in[21];
    const float* Wp    = (const float*)d_in[22];
    const float* bp    = (const float*)d_in[23];

    // workspace (~101 MB): fp16 stream only
    char* wp8 = (char*)d_ws;
    unsigned short* h_f16  = (unsigned short*)wp8;     wp8 += (size_t)M * D * 2;
    unsigned short* blockA = (unsigned short*)wp8;     wp8 += (size_t)M * F * 2;
    unsigned short* qk_f   = blockA;                         // M*1536
    unsigned short* v_t    = blockA + (size_t)M * NQK;       // 48*64*1024
    unsigned short* attno  = v_t + (size_t)B * H * 64 * S;   // M*768
    unsigned short* inter  = blockA;                         // M*F (aliases all three)
    unsigned short* wo_part = blockA;                        // 3 x M*D fp16 (qk+v_t dead)
    char*           oproj8 = wp8;                      wp8 += (size_t)M * D * 4;
    unsigned short* f2_part = (unsigned short*)oproj8;       // 2 x M*D fp16
    unsigned short* Wqkv_t = (unsigned short*)wp8;     wp8 += (size_t)L * NQKV * D * 2;
    unsigned short* Wo_t   = (unsigned short*)wp8;     wp8 += (size_t)L * D * D * 2;
    unsigned short* W1_t   = (unsigned short*)wp8;     wp8 += (size_t)L * F * D * 2;
    unsigned short* W2_t   = (unsigned short*)wp8;     wp8 += (size_t)L * D * F * 2;
    float*          bqkv   = (float*)wp8;              wp8 += (size_t)L * NQKV * 4;
    float*          ppart  = (float*)wp8;                    // 4*16*768 fp32

    // fused weight prep: 6912 64x64 transpose tiles + 36 bias blocks, one dispatch
    weight_prep_kernel<<<6948, 256, 0, stream>>>(
        Wq, Wk, Wv, Wo, W1, W2, bq, bk, bv, Wqkv_t, Wo_t, W1_t, W2_t, bqkv);

    embed_ln_kernel<<<M, 192, 0, stream>>>(x, we, pe, te, emb_g, emb_b, h_f16);

    for (int l = 0; l < L; ++l) {
        gemm_qkv_kernel<<<dim3(NQKV / 128, M / 128), 256, 0, stream>>>(
            h_f16, Wqkv_t + (size_t)l * NQKV * D, bqkv + l * NQKV, qk_f, v_t);

        attention_kernel<<<(S / 64) * B * H, 256, 0, stream>>>(qk_f, v_t, attno);

        // O-proj: split-K=3 (K=768 -> 3x256), fp16 partials into dead qk|v region
        gemm_splitk_kernel<<<dim3(D / 128, M / 128, 3), 256, 0, stream>>>(
            attno, Wo_t + (size_t)l * D * D, wo_part, nullptr, 3, D, D, 256);
        ln_reduce_kernel<3, 0, false, true><<<M, 192, 0, stream>>>(
            wo_part, nullptr, bo + l * D, h_f16, ln1_g + l * D, ln1_b + l * D, h_f16);

        gemm_mfma_kernel<1, unsigned short><<<dim3(F / 128, M / 128), 256, 0, stream>>>(
            h_f16, W1_t + (size_t)l * F * D, b1 + l * F, inter, F, D);

        // FFN2: split-K=3; parts 0,1 in oproj region, part 2 in dead h_f16
        gemm_splitk_kernel<<<dim3(D / 128, M / 128, 3), 256, 0, stream>>>(
            inter, W2_t + (size_t)l * D * F, f2_part, h_f16, 2, D, F, 1024);
        ln_reduce_kernel<2, 1, true, false><<<M, 192, 0, stream>>>(
            f2_part, h_f16, b2 + l * D, nullptr, ln2_g + l * D, ln2_b + l * D, h_f16);
    }

    pooler_partial_kernel<<<dim3(16, B), 768, 0, stream>>>(h_f16, Wp, ppart);
    pooler_reduce_kernel<<<B, 768, 0, stream>>>(ppart, bp, (float*)d_out);
}

// Round 18
// 693.927 us; speedup vs baseline: 1.0076x; 1.0011x over previous
//
#include <hip/hip_runtime.h>
#include <math.h>

namespace {

constexpr int B  = 4;
constexpr int S  = 1024;
constexpr int D  = 768;
constexpr int H  = 12;
constexpr int HD = 64;
constexpr int F  = 3072;
constexpr int L  = 4;
constexpr int M  = B * S;       // 4096 tokens
constexpr int NQKV = 3 * D;     // 2304
constexpr int NQK = 2 * D;      // 1536 (q|k packed)

typedef __attribute__((ext_vector_type(4))) float    f32x4;
typedef _Float16 f16x8 __attribute__((ext_vector_type(8)));
typedef __attribute__((ext_vector_type(8))) unsigned short u16x8;
typedef __attribute__((ext_vector_type(4))) unsigned short u16x4;

__device__ __forceinline__ unsigned short f2h_u(float f) {
    _Float16 h = (_Float16)f;
    return __builtin_bit_cast(unsigned short, h);
}
__device__ __forceinline__ float h2f(unsigned short u) {
    return (float)__builtin_bit_cast(_Float16, u);
}

__device__ __forceinline__ void gload16(const void* gptr, void* ldsptr) {
    __builtin_amdgcn_global_load_lds(
        (const __attribute__((address_space(1))) unsigned int*)gptr,
        (__attribute__((address_space(3))) unsigned int*)ldsptr,
        16, 0, 0);
}

// ---------------- reductions ----------------
__device__ __forceinline__ float wave_sum(float v) {
#pragma unroll
    for (int off = 32; off; off >>= 1) v += __shfl_xor(v, off, 64);
    return v;
}
// 192-thread (3-wave) block reduce
__device__ __forceinline__ float block_sum192(float v, float* sm) {
    v = wave_sum(v);
    __syncthreads();
    if ((threadIdx.x & 63) == 0) sm[threadIdx.x >> 6] = v;
    __syncthreads();
    return sm[0] + sm[1] + sm[2];
}
// 256-thread (4-wave) block reduce (inactive lanes contribute 0)
__device__ __forceinline__ float block_sum256(float v, float* sm) {
    v = wave_sum(v);
    __syncthreads();
    if ((threadIdx.x & 63) == 0) sm[threadIdx.x >> 6] = v;
    __syncthreads();
    return sm[0] + sm[1] + sm[2] + sm[3];
}

// ---------------- fused prep: weight transposes + bias concat + embed+LN ----------
// All three are mutually independent producers for layer 0; one dispatch lets the
// ~7-9 us embed+LN hide entirely under the 55 us weight-prep (round-18 fusion).
// NOTE (rounds 14-16): three optimization attempts on the transpose itself (32x32
// grid variant, 64x64 tiles, pipelined 64x256 stripes) all measured neutral at
// ~54-56 us; mechanism of its ~50%-of-BW ceiling remains unidentified.
__device__ __forceinline__ void transpose_tile64(const float* __restrict__ src,
                                                 unsigned short* __restrict__ dst,
                                                 int R, int C, int rb, int cb,
                                                 float (*tile)[65]) {
    const int t = threadIdx.x;
    const int r = t >> 2;
    const int q4 = t & 3;
#pragma unroll
    for (int k = 0; k < 4; ++k) {
        const int cq = (q4 + k * 4) * 4;
        const float4 v = *(const float4*)&src[(size_t)(rb + r) * C + cb + cq];
        tile[r][cq + 0] = v.x; tile[r][cq + 1] = v.y;
        tile[r][cq + 2] = v.z; tile[r][cq + 3] = v.w;
    }
    __syncthreads();
    const int dc = t >> 2;
    const int s8 = t & 3;
#pragma unroll
    for (int k = 0; k < 2; ++k) {
        const int rq = (s8 + k * 4) * 8;
        u16x8 o;
#pragma unroll
        for (int j = 0; j < 8; ++j) o[j] = f2h_u(tile[rq + j][dc]);
        *(u16x8*)&dst[(size_t)(cb + dc) * R + rb + rq] = o;
    }
}

__global__ __launch_bounds__(256) void prep_embed_kernel(
    const float* __restrict__ Wq, const float* __restrict__ Wk,
    const float* __restrict__ Wv, const float* __restrict__ Wo,
    const float* __restrict__ W1, const float* __restrict__ W2,
    const float* __restrict__ bq, const float* __restrict__ bk,
    const float* __restrict__ bv,
    const int* __restrict__ x, const float* __restrict__ we,
    const float* __restrict__ pe, const float* __restrict__ te,
    const float* __restrict__ emb_g, const float* __restrict__ emb_b,
    unsigned short* __restrict__ Wqkv_t, unsigned short* __restrict__ Wo_t,
    unsigned short* __restrict__ W1_t, unsigned short* __restrict__ W2_t,
    float* __restrict__ bqkv, unsigned short* __restrict__ hh) {
    __shared__ float tile[64][65];   // transpose staging / embed reduce scratch (union)
    const int tid = blockIdx.x;
    if (tid < 2304) {                        // Wq/Wk/Wv/Wo : DxD, 144 tiles each
        const int w = tid / 144, rem = tid % 144;
        const int l = w >> 2, which = w & 3;
        const float* src = (which == 0 ? Wq : which == 1 ? Wk : which == 2 ? Wv : Wo)
                           + (size_t)l * D * D;
        unsigned short* dst = (which < 3)
            ? Wqkv_t + ((size_t)l * NQKV + which * D) * D
            : Wo_t + (size_t)l * D * D;
        transpose_tile64(src, dst, D, D, (rem / 12) * 64, (rem % 12) * 64, tile);
    } else if (tid < 4608) {                 // W1 : R=D, C=F -> [F][D], 576 tiles/l
        const int t2 = tid - 2304, l = t2 / 576, rem = t2 % 576;
        transpose_tile64(W1 + (size_t)l * D * F, W1_t + (size_t)l * F * D,
                         D, F, (rem / 48) * 64, (rem % 48) * 64, tile);
    } else if (tid < 6912) {                 // W2 : R=F, C=D -> [D][F], 576 tiles/l
        const int t2 = tid - 4608, l = t2 / 576, rem = t2 % 576;
        transpose_tile64(W2 + (size_t)l * F * D, W2_t + (size_t)l * D * F,
                         F, D, (rem / 12) * 64, (rem % 12) * 64, tile);
    } else if (tid < 6948) {                 // bias concat (36 blocks)
        const int i = (tid - 6912) * 256 + threadIdx.x;
        if (i < L * NQKV) {
            const int l = i / NQKV, j = i % NQKV;
            bqkv[i] = (j < D) ? bq[l * D + j]
                    : (j < 2 * D) ? bk[l * D + j - D] : bv[l * D + j - 2 * D];
        }
    } else {                                 // embeddings + LayerNorm (4096 blocks)
        float* sm = &tile[0][0];
        const int row = tid - 6948;
        const int s = row & (S - 1);
        const int tok = x[row];
        const int t = threadIdx.x;
        const bool act = t < 192;
        const int d = t * 4;
        float v[4] = {};
        if (act) {
            const float4 w = *(const float4*)&we[(size_t)tok * D + d];
            const float4 p = *(const float4*)&pe[(size_t)s * D + d];
            const float4 tt = *(const float4*)&te[d];
            v[0] = w.x + p.x + tt.x; v[1] = w.y + p.y + tt.y;
            v[2] = w.z + p.z + tt.z; v[3] = w.w + p.w + tt.w;
        }
        const float mu = block_sum256(v[0] + v[1] + v[2] + v[3], sm) * (1.0f / D);
        float lvar = 0.f;
        if (act) {
#pragma unroll
            for (int i = 0; i < 4; ++i) { float dv = v[i] - mu; lvar += dv * dv; }
        }
        const float var = block_sum256(lvar, sm) * (1.0f / D);
        const float inv = rsqrtf(var + 1e-12f);
        if (act) {
            const float4 g4 = *(const float4*)&emb_g[d];
            const float4 b4 = *(const float4*)&emb_b[d];
            u16x4 ob;
            ob[0] = f2h_u((v[0] - mu) * inv * g4.x + b4.x);
            ob[1] = f2h_u((v[1] - mu) * inv * g4.y + b4.y);
            ob[2] = f2h_u((v[2] - mu) * inv * g4.z + b4.z);
            ob[3] = f2h_u((v[3] - mu) * inv * g4.w + b4.w);
            *(u16x4*)&hh[(size_t)row * D + d] = ob;
        }
    }
}

// ------- partial-sum reduce + (opt GELU / fp16 residual) + LayerNorm (192 thr) -----
// Row-local in-place safe: all row reads (parts, res) complete before the first
// reduction barrier; the write happens after. outh may alias res or a pB part.
template <int NPA, int NPB, bool GELU_, bool HAS_RES>
__global__ __launch_bounds__(192) void ln_reduce_kernel(
    const unsigned short* __restrict__ pA,      // NPA x [M][D] fp16 (contiguous)
    const unsigned short* __restrict__ pB,      // NPB x [M][D] fp16 (contiguous) or null
    const float* __restrict__ bias,             // [D]
    const unsigned short* __restrict__ res,     // [M][D] fp16 or nullptr
    const float* __restrict__ g, const float* __restrict__ bb,
    unsigned short* __restrict__ outh) {
    __shared__ float sm[3];
    const int row = blockIdx.x;
    const int t = threadIdx.x;
    const int d = t * 4;
    float v[4];
    const float4 bi = *(const float4*)&bias[d];
    v[0] = bi.x; v[1] = bi.y; v[2] = bi.z; v[3] = bi.w;
#pragma unroll
    for (int pp = 0; pp < NPA; ++pp) {
        const u16x4 pu = *(const u16x4*)&pA[(size_t)pp * M * D + (size_t)row * D + d];
#pragma unroll
        for (int i = 0; i < 4; ++i) v[i] += h2f(pu[i]);
    }
#pragma unroll
    for (int pp = 0; pp < NPB; ++pp) {
        const u16x4 pu = *(const u16x4*)&pB[(size_t)pp * M * D + (size_t)row * D + d];
#pragma unroll
        for (int i = 0; i < 4; ++i) v[i] += h2f(pu[i]);
    }
    if (HAS_RES) {
        const u16x4 rv = *(const u16x4*)&res[(size_t)row * D + d];
#pragma unroll
        for (int i = 0; i < 4; ++i) v[i] += h2f(rv[i]);
    }
    if (GELU_) {
#pragma unroll
        for (int i = 0; i < 4; ++i)
            v[i] = 0.5f * v[i] * (1.0f + erff(v[i] * 0.70710678118654752f));
    }
    const float mu = block_sum192(v[0] + v[1] + v[2] + v[3], sm) * (1.0f / D);
    float lvar = 0.f;
#pragma unroll
    for (int i = 0; i < 4; ++i) { float dv = v[i] - mu; lvar += dv * dv; }
    const float var = block_sum192(lvar, sm) * (1.0f / D);
    const float inv = rsqrtf(var + 1e-12f);
    const float4 g4 = *(const float4*)&g[d];
    const float4 b4 = *(const float4*)&bb[d];
    u16x4 ob;
    ob[0] = f2h_u((v[0] - mu) * inv * g4.x + b4.x);
    ob[1] = f2h_u((v[1] - mu) * inv * g4.y + b4.y);
    ob[2] = f2h_u((v[2] - mu) * inv * g4.z + b4.z);
    ob[3] = f2h_u((v[3] - mu) * inv * g4.w + b4.w);
    *(u16x4*)&outh[(size_t)row * D + d] = ob;
}

// ======== shared fp16 MFMA GEMM body: 128x128 tile, BK=32, 4 waves ========
// 3-buffer pipeline, counted vmcnt(4); T1 XCD-swizzled block ids; T5 setprio.
// 48 KB LDS -> 3 blocks/CU (proven optimum: 72 KB/2-blk was -45%, 32 KB/5-blk neutral).
#define GEMM_STAGE(buf, k0)                                                          \
    do {                                                                             \
        gload16(Ab + (size_t)(rowBase + r0) * LDA + (k0) + c0 * 8, &Asl[buf][ldsOff0]); \
        gload16(Ab + (size_t)(rowBase + r1) * LDA + (k0) + c1 * 8, &Asl[buf][ldsOff1]); \
        gload16(Bb + (size_t)(colBase + r0) * LDA + (k0) + c0 * 8, &Bsl[buf][ldsOff0]); \
        gload16(Bb + (size_t)(colBase + r1) * LDA + (k0) + c1 * 8, &Bsl[buf][ldsOff1]); \
    } while (0)

#define GEMM_BODY(A_, Bw_, LDA_, KLEN_)                                              \
    constexpr int BK = 32;                                                           \
    __shared__ unsigned short Asl[3][128 * BK];                                      \
    __shared__ unsigned short Bsl[3][128 * BK];                                      \
    const unsigned short* Ab = (A_);                                                 \
    const unsigned short* Bb = (Bw_);                                                \
    const int LDA = (LDA_);                                                          \
    const int t = threadIdx.x;                                                       \
    const int lane = t & 63;                                                         \
    const int wid = t >> 6;                                                          \
    const int lr = lane & 15;                                                        \
    const int kh = lane >> 4;                                                        \
    const int wrBase = (wid >> 1) * 64;                                              \
    const int wcBase = (wid & 1) * 64;                                               \
    const int nwg = gridDim.x * gridDim.y;                                           \
    const int flatid = blockIdx.y * gridDim.x + blockIdx.x;                          \
    const int swzid = (flatid & 7) * (nwg >> 3) + (flatid >> 3);                     \
    const int rowBase = (swzid / gridDim.x) * 128;                                   \
    const int colBase = (swzid % gridDim.x) * 128;                                   \
    f32x4 acc[4][4] = {};                                                            \
    const int r0 = t >> 2, c0 = (t & 3) ^ ((r0 >> 1) & 3);                           \
    const int s_hi = 256 + t;                                                        \
    const int r1 = s_hi >> 2, c1 = (s_hi & 3) ^ ((r1 >> 1) & 3);                     \
    const unsigned ldsOff0 = (unsigned)((t & 192) * 8);                              \
    const unsigned ldsOff1 = (unsigned)((256 + (t & 192)) * 8);                      \
    const int nt = (KLEN_) / BK;                                                     \
    GEMM_STAGE(0, 0);                                                                \
    GEMM_STAGE(1, BK);                                                               \
    int p = 0;                                                                       \
    for (int tt = 0; tt < nt; ++tt) {                                                \
        if (tt + 1 < nt) asm volatile("s_waitcnt vmcnt(4)" ::: "memory");            \
        else             asm volatile("s_waitcnt vmcnt(0)" ::: "memory");            \
        __builtin_amdgcn_s_barrier();                                                \
        __builtin_amdgcn_sched_barrier(0);                                           \
        if (tt + 2 < nt) {                                                           \
            int nb = p + 2; if (nb >= 3) nb -= 3;                                    \
            GEMM_STAGE(nb, (tt + 2) * BK);                                           \
        }                                                                            \
        f16x8 af[4], bfr[4];                                                         \
        _Pragma("unroll")                                                            \
        for (int mi = 0; mi < 4; ++mi) {                                             \
            const int ar = wrBase + mi * 16 + lr;                                    \
            const int ch = kh ^ ((ar >> 1) & 3);                                     \
            af[mi] = *(const f16x8*)&Asl[p][ar * BK + ch * 8];                       \
        }                                                                            \
        _Pragma("unroll")                                                            \
        for (int nj = 0; nj < 4; ++nj) {                                             \
            const int bc = wcBase + nj * 16 + lr;                                    \
            const int ch = kh ^ ((bc >> 1) & 3);                                     \
            bfr[nj] = *(const f16x8*)&Bsl[p][bc * BK + ch * 8];                      \
        }                                                                            \
        __builtin_amdgcn_s_setprio(1);                                               \
        _Pragma("unroll")                                                            \
        for (int mi = 0; mi < 4; ++mi)                                               \
            _Pragma("unroll")                                                        \
            for (int nj = 0; nj < 4; ++nj)                                           \
                acc[mi][nj] = __builtin_amdgcn_mfma_f32_16x16x32_f16(                \
                    af[mi], bfr[nj], acc[mi][nj], 0, 0, 0);                          \
        __builtin_amdgcn_s_setprio(0);                                               \
        p = (p == 2) ? 0 : p + 1;                                                    \
    }

// ---------------- generic GEMM: C[M,N] = A @ Bw^T + bias; CT=float|ushort(fp16) ----
template <int EPI, typename CT>
__global__ __launch_bounds__(256) void gemm_mfma_kernel(
    const unsigned short* __restrict__ A, const unsigned short* __restrict__ Bw,
    const float* __restrict__ bias, CT* __restrict__ C, int N, int K) {
    GEMM_BODY(A, Bw, K, K)
#pragma unroll
    for (int nj = 0; nj < 4; ++nj) {
        const int col = colBase + wcBase + nj * 16 + lr;
        const float bc = bias[col];
#pragma unroll
        for (int mi = 0; mi < 4; ++mi) {
            const int row = rowBase + wrBase + mi * 16 + kh * 4;
#pragma unroll
            for (int j = 0; j < 4; ++j) {
                float v = acc[mi][nj][j] + bc;
                if (EPI == 1) v = 0.5f * v * (1.0f + erff(v * 0.70710678118654752f));
                if constexpr (sizeof(CT) == 4) C[(size_t)(row + j) * N + col] = v;
                else                           C[(size_t)(row + j) * N + col] = f2h_u(v);
            }
        }
    }
}

// ------- split-K GEMM: part z -> (z < ZA ? CpA + z : CpB + z-ZA)[M][N] fp16 -------
__global__ __launch_bounds__(256) void gemm_splitk_kernel(
    const unsigned short* __restrict__ A, const unsigned short* __restrict__ Bw,
    unsigned short* __restrict__ CpA, unsigned short* __restrict__ CpB,
    int ZA, int N, int Kfull, int Kc) {
    const int z = blockIdx.z;
    GEMM_BODY(A + (size_t)z * Kc, Bw + (size_t)z * Kc, Kfull, Kc)
    unsigned short* Cp = (z < ZA) ? (CpA + (size_t)z * M * N)
                                  : (CpB + (size_t)(z - ZA) * M * N);
#pragma unroll
    for (int nj = 0; nj < 4; ++nj) {
        const int col = colBase + wcBase + nj * 16 + lr;
#pragma unroll
        for (int mi = 0; mi < 4; ++mi) {
            const int row = rowBase + wrBase + mi * 16 + kh * 4;
#pragma unroll
            for (int j = 0; j < 4; ++j)
                Cp[(size_t)(row + j) * N + col] = f2h_u(acc[mi][nj][j]);
        }
    }
}

// ---------------- QKV GEMM: q,k -> qkout [M][1536]; v -> vtout [BH][64][S] (V^T) ----
__global__ __launch_bounds__(256) void gemm_qkv_kernel(
    const unsigned short* __restrict__ A, const unsigned short* __restrict__ Bw,
    const float* __restrict__ bias, unsigned short* __restrict__ qkout,
    unsigned short* __restrict__ vtout) {
    GEMM_BODY(A, Bw, D, D)
    const bool isV = (colBase >= NQK);   // 128-aligned boundary -> block-uniform
#pragma unroll
    for (int nj = 0; nj < 4; ++nj) {
        const int col = colBase + wcBase + nj * 16 + lr;
        const float bc = bias[col];
        if (!isV) {
#pragma unroll
            for (int mi = 0; mi < 4; ++mi) {
                const int row = rowBase + wrBase + mi * 16 + kh * 4;
#pragma unroll
                for (int j = 0; j < 4; ++j)
                    qkout[(size_t)(row + j) * NQK + col] = f2h_u(acc[mi][nj][j] + bc);
            }
        } else {
            const int dd = col - NQK;
            const int h2 = dd >> 6, d6 = dd & 63;
#pragma unroll
            for (int mi = 0; mi < 4; ++mi) {
                const int row = rowBase + wrBase + mi * 16 + kh * 4;
                const int b2 = row >> 10, s2 = row & 1023;
                u16x4 ov;
#pragma unroll
                for (int j = 0; j < 4; ++j) ov[j] = f2h_u(acc[mi][nj][j] + bc);
                *(u16x4*)&vtout[(((size_t)(b2 * H + h2)) * 64 + d6) * S + s2] = ov;
            }
        }
    }
}

// ---------------- MFMA flash attention (double-buffered, 1 barrier/tile) ----------------
// 1-D grid (768 blocks) with XCD swizzle: the 16 q-tile blocks sharing one (b,h)'s
// K/V are consecutive post-swizzle -> same XCD L2.
__global__ __launch_bounds__(256) void attention_kernel(
    const unsigned short* __restrict__ qk,   // [M][1536] fp16 (q|k)
    const unsigned short* __restrict__ vt,   // [BH][64][S] fp16 (V^T per head)
    unsigned short* __restrict__ o) {        // [M][768] fp16
    __shared__ unsigned short Qs[64 * 64];
    __shared__ unsigned short Ks[2][64 * 64];
    __shared__ unsigned short Vt[2][64 * 64];
    __shared__ _Float16 Ps[4][16 * 64];

    const int t = threadIdx.x;
    const int nwg = gridDim.x;                       // 768
    const int flatid = blockIdx.x;
    const int lin = (flatid & 7) * (nwg >> 3) + (flatid >> 3);
    const int qt = lin & 15;
    const int bh = lin >> 4;
    const int b = bh / H, hh = bh % H;
    const int w = t >> 6;
    const int lr = t & 15;
    const int kh = (t >> 4) & 3;

    const int r0 = t >> 3;
    const int g0 = (t & 7) ^ (r0 & 7);
    const unsigned lo0 = (unsigned)((t & 192) * 8);
    const unsigned lo1 = (unsigned)(2048 + (t & 192) * 8);

    const unsigned short* kgb = qk + D + hh * HD;
    const unsigned short* vgb = vt + (size_t)bh * 64 * S;

    {
        const size_t qrow0 = (size_t)(b * S + qt * 64);
        gload16(qk + (qrow0 + r0) * NQK + hh * HD + g0 * 8, &Qs[lo0]);
        gload16(qk + (qrow0 + r0 + 32) * NQK + hh * HD + g0 * 8, &Qs[lo1]);
        gload16(kgb + (size_t)(b * S + r0) * NQK + g0 * 8, &Ks[0][lo0]);
        gload16(kgb + (size_t)(b * S + r0 + 32) * NQK + g0 * 8, &Ks[0][lo1]);
        gload16(vgb + (size_t)r0 * S + g0 * 8, &Vt[0][lo0]);
        gload16(vgb + (size_t)(r0 + 32) * S + g0 * 8, &Vt[0][lo1]);
    }
    __syncthreads();

    float m_[4] = {-INFINITY, -INFINITY, -INFINITY, -INFINITY};
    float l_[4] = {};
    f32x4 oacc[4] = {};
    const int swlo = (kh)     ^ (lr & 7);
    const int swhi = (kh + 4) ^ (lr & 7);
    constexpr int NT = S / 64;

    for (int it = 0; it < NT; ++it) {
        const int cur = it & 1;
        if (it + 1 < NT) {
            const int kt = (it + 1) * 64;
            gload16(kgb + (size_t)(b * S + kt + r0) * NQK + g0 * 8, &Ks[cur ^ 1][lo0]);
            gload16(kgb + (size_t)(b * S + kt + r0 + 32) * NQK + g0 * 8, &Ks[cur ^ 1][lo1]);
            gload16(vgb + (size_t)r0 * S + kt + g0 * 8, &Vt[cur ^ 1][lo0]);
            gload16(vgb + (size_t)(r0 + 32) * S + kt + g0 * 8, &Vt[cur ^ 1][lo1]);
        }

        const int qr = w * 16 + lr;
        f16x8 aq0 = *(const f16x8*)&Qs[qr * 64 + swlo * 8];
        f16x8 aq1 = *(const f16x8*)&Qs[qr * 64 + swhi * 8];
        f32x4 sc[4];
        __builtin_amdgcn_s_setprio(1);
#pragma unroll
        for (int nj = 0; nj < 4; ++nj) {
            const int kr = nj * 16 + lr;
            f16x8 b0 = *(const f16x8*)&Ks[cur][kr * 64 + swlo * 8];
            f16x8 b1 = *(const f16x8*)&Ks[cur][kr * 64 + swhi * 8];
            f32x4 z = {};
            z = __builtin_amdgcn_mfma_f32_16x16x32_f16(aq0, b0, z, 0, 0, 0);
            z = __builtin_amdgcn_mfma_f32_16x16x32_f16(aq1, b1, z, 0, 0, 0);
            sc[nj] = z;
        }
        __builtin_amdgcn_s_setprio(0);

        float alpha[4];
#pragma unroll
        for (int j = 0; j < 4; ++j) {
            float rm = fmaxf(fmaxf(sc[0][j], sc[1][j]), fmaxf(sc[2][j], sc[3][j])) * 0.125f;
#pragma unroll
            for (int off = 1; off < 16; off <<= 1) rm = fmaxf(rm, __shfl_xor(rm, off, 64));
            const float mn = fmaxf(m_[j], rm);
            alpha[j] = __expf(m_[j] - mn);
            m_[j] = mn;
        }
        float ph[4][4];
        float rs[4] = {};
#pragma unroll
        for (int nj = 0; nj < 4; ++nj)
#pragma unroll
            for (int j = 0; j < 4; ++j) {
                float p2 = __expf(fmaf(sc[nj][j], 0.125f, -m_[j]));
                ph[nj][j] = p2;
                rs[j] += p2;
            }
#pragma unroll
        for (int j = 0; j < 4; ++j) {
#pragma unroll
            for (int off = 1; off < 16; off <<= 1) rs[j] += __shfl_xor(rs[j], off, 64);
            l_[j] = l_[j] * alpha[j] + rs[j];
        }
        _Float16* psw = &Ps[w][0];
#pragma unroll
        for (int nj = 0; nj < 4; ++nj)
#pragma unroll
            for (int j = 0; j < 4; ++j) {
                const int pr = kh * 4 + j;
                const int pc = nj * 16 + lr;
                psw[pr * 64 + (((pc >> 3) ^ (pr & 7)) * 8) + (pc & 7)] = (_Float16)ph[nj][j];
            }
#pragma unroll
        for (int nj = 0; nj < 4; ++nj)
#pragma unroll
            for (int j = 0; j < 4; ++j) oacc[nj][j] *= alpha[j];

        f16x8 pa0 = *(const f16x8*)&psw[lr * 64 + swlo * 8];
        f16x8 pa1 = *(const f16x8*)&psw[lr * 64 + swhi * 8];
        __builtin_amdgcn_s_setprio(1);
#pragma unroll
        for (int nj = 0; nj < 4; ++nj) {
            const int vr = nj * 16 + lr;
            f16x8 b0 = *(const f16x8*)&Vt[cur][vr * 64 + swlo * 8];
            f16x8 b1 = *(const f16x8*)&Vt[cur][vr * 64 + swhi * 8];
            oacc[nj] = __builtin_amdgcn_mfma_f32_16x16x32_f16(pa0, b0, oacc[nj], 0, 0, 0);
            oacc[nj] = __builtin_amdgcn_mfma_f32_16x16x32_f16(pa1, b1, oacc[nj], 0, 0, 0);
        }
        __builtin_amdgcn_s_setprio(0);

        __syncthreads();
    }

    float inv[4];
#pragma unroll
    for (int j = 0; j < 4; ++j) inv[j] = 1.0f / l_[j];
#pragma unroll
    for (int nj = 0; nj < 4; ++nj)
#pragma unroll
        for (int j = 0; j < 4; ++j) {
            const int token = b * S + qt * 64 + w * 16 + kh * 4 + j;
            o[(size_t)token * D + hh * HD + nj * 16 + lr] = f2h_u(oacc[nj][j] * inv[j]);
        }
}

// ---------------- pooler: split-K partial + reduce (fp16 h) ----------------
__global__ __launch_bounds__(768) void pooler_partial_kernel(
    const unsigned short* __restrict__ h, const float* __restrict__ Wp,
    float* __restrict__ partial) {
    const int slice = blockIdx.x;
    const int b = blockIdx.y;
    const int d = threadIdx.x;
    const unsigned short* hrow = h + (size_t)b * S * D + slice * 48;
    const float* wcol = Wp + (size_t)slice * 48 * D + d;
    float acc = 0.f;
#pragma unroll
    for (int kk = 0; kk < 48; ++kk) acc = fmaf(h2f(hrow[kk]), wcol[(size_t)kk * D], acc);
    partial[((size_t)b * 16 + slice) * D + d] = acc;
}

__global__ __launch_bounds__(768) void pooler_reduce_kernel(
    const float* __restrict__ partial, const float* __restrict__ bp,
    float* __restrict__ out) {
    const int b = blockIdx.x;
    const int d = threadIdx.x;
    float acc = bp[d];
#pragma unroll
    for (int s2 = 0; s2 < 16; ++s2) acc += partial[((size_t)b * 16 + s2) * D + d];
    out[(size_t)b * D + d] = tanhf(acc);
}

}  // namespace

extern "C" void kernel_launch(void* const* d_in, const int* in_sizes, int n_in,
                              void* d_out, int out_size, void* d_ws, size_t ws_size,
                              hipStream_t stream) {
    (void)in_sizes; (void)n_in; (void)out_size; (void)ws_size;

    const int*   x     = (const int*)  d_in[0];
    const float* we    = (const float*)d_in[1];
    const float* pe    = (const float*)d_in[2];
    const float* te    = (const float*)d_in[3];
    const float* emb_g = (const float*)d_in[4];
    const float* emb_b = (const float*)d_in[5];
    const float* Wq    = (const float*)d_in[6];
    const float* bq    = (const float*)d_in[7];
    const float* Wk    = (const float*)d_in[8];
    const float* bk    = (const float*)d_in[9];
    const float* Wv    = (const float*)d_in[10];
    const float* bv    = (const float*)d_in[11];
    const float* Wo    = (const float*)d_in[12];
    const float* bo    = (const float*)d_in[13];
    const float* ln1_g = (const float*)d_in[14];
    const float* ln1_b = (const float*)d_in[15];
    const float* W1    = (const float*)d_in[16];
    const float* b1    = (const float*)d_in[17];
    const float* W2    = (const float*)d_in[18];
    const float* b2    = (const float*)d_in[19];
    const float* ln2_g = (const float*)d_in[20];
    const float* ln2_b = (const float*)d_in[21];
    const float* Wp    = (const float*)d_in[22];
    const float* bp    = (const float*)d_in[23];

    // workspace (~101 MB): fp16 stream only
    char* wp8 = (char*)d_ws;
    unsigned short* h_f16  = (unsigned short*)wp8;     wp8 += (size_t)M * D * 2;
    unsigned short* blockA = (unsigned short*)wp8;     wp8 += (size_t)M * F * 2;
    unsigned short* qk_f   = blockA;                         // M*1536
    unsigned short* v_t    = blockA + (size_t)M * NQK;       // 48*64*1024
    unsigned short* attno  = v_t + (size_t)B * H * 64 * S;   // M*768
    unsigned short* inter  = blockA;                         // M*F (aliases all three)
    unsigned short* wo_part = blockA;                        // 3 x M*D fp16 (qk+v_t dead)
    char*           oproj8 = wp8;                      wp8 += (size_t)M * D * 4;
    unsigned short* f2_part = (unsigned short*)oproj8;       // 2 x M*D fp16
    unsigned short* Wqkv_t = (unsigned short*)wp8;     wp8 += (size_t)L * NQKV * D * 2;
    unsigned short* Wo_t   = (unsigned short*)wp8;     wp8 += (size_t)L * D * D * 2;
    unsigned short* W1_t   = (unsigned short*)wp8;     wp8 += (size_t)L * F * D * 2;
    unsigned short* W2_t   = (unsigned short*)wp8;     wp8 += (size_t)L * D * F * 2;
    float*          bqkv   = (float*)wp8;              wp8 += (size_t)L * NQKV * 4;
    float*          ppart  = (float*)wp8;                    // 4*16*768 fp32

    // fused prep: 6912 weight-transpose tiles + 36 bias blocks + 4096 embed+LN rows
    prep_embed_kernel<<<6948 + M, 256, 0, stream>>>(
        Wq, Wk, Wv, Wo, W1, W2, bq, bk, bv,
        x, we, pe, te, emb_g, emb_b,
        Wqkv_t, Wo_t, W1_t, W2_t, bqkv, h_f16);

    for (int l = 0; l < L; ++l) {
        gemm_qkv_kernel<<<dim3(NQKV / 128, M / 128), 256, 0, stream>>>(
            h_f16, Wqkv_t + (size_t)l * NQKV * D, bqkv + l * NQKV, qk_f, v_t);

        attention_kernel<<<(S / 64) * B * H, 256, 0, stream>>>(qk_f, v_t, attno);

        // O-proj: split-K=3 (K=768 -> 3x256), fp16 partials into dead qk|v region
        gemm_splitk_kernel<<<dim3(D / 128, M / 128, 3), 256, 0, stream>>>(
            attno, Wo_t + (size_t)l * D * D, wo_part, nullptr, 3, D, D, 256);
        ln_reduce_kernel<3, 0, false, true><<<M, 192, 0, stream>>>(
            wo_part, nullptr, bo + l * D, h_f16, ln1_g + l * D, ln1_b + l * D, h_f16);

        gemm_mfma_kernel<1, unsigned short><<<dim3(F / 128, M / 128), 256, 0, stream>>>(
            h_f16, W1_t + (size_t)l * F * D, b1 + l * F, inter, F, D);

        // FFN2: split-K=3; parts 0,1 in oproj region, part 2 in dead h_f16
        gemm_splitk_kernel<<<dim3(D / 128, M / 128, 3), 256, 0, stream>>>(
            inter, W2_t + (size_t)l * D * F, f2_part, h_f16, 2, D, F, 1024);
        ln_reduce_kernel<2, 1, true, false><<<M, 192, 0, stream>>>(
            f2_part, h_f16, b2 + l * D, nullptr, ln2_g + l * D, ln2_b + l * D, h_f16);
    }

    pooler_partial_kernel<<<dim3(16, B), 768, 0, stream>>>(h_f16, Wp, ppart);
    pooler_reduce_kernel<<<B, 768, 0, stream>>>(ppart, bp, (float*)d_out);
}